// Round 8
// baseline (307.874 us; speedup 1.0000x reference)
//
#include <hip/hip_runtime.h>

static constexpr int B_    = 64;
static constexpr int N_    = 2048;
static constexpr int DI_   = 8;
static constexpr int O_    = 32;
static constexpr int P_    = 16;
static constexpr int OP_   = O_ * P_;      // 512
static constexpr int M_    = OP_ * B_;     // 32768 s elements
static constexpr int CHUNK_ = 8;
static constexpr int NBLK_  = N_ / CHUNK_; // 256 n-chunks
static constexpr int WSLICE_ = O_ * P_ * DI_;  // 4096 floats per n

// DPP add helper: v + dpp_mov(v). CTRL compile-time (0xB1 quad_perm[1,0,3,2];
// 0x121/2/4/8 = row_ror 1/2/4/8).
template <int CTRL>
__device__ __forceinline__ float dpp_add(float v) {
  int t = __builtin_amdgcn_update_dpp(0, __float_as_int(v), CTRL, 0xf, 0xf, false);
  return v + __int_as_float(t);
}

__device__ __forceinline__ float rfl(float v) {
  return __int_as_float(__builtin_amdgcn_readfirstlane(__float_as_int(v)));
}

// R8: the 46-50us plateau (R1/R4/R7, MODE-invariant) is wave COUPLING through
// the shared LDS W-tile: every wave rendezvouses with staging each (2-)nn, so
// the slowest wave paces all of them; 60% of wave time is exposed stall no
// matter how the barriers/prefetch are arranged. Fix: decouple entirely.
//  - W register-direct from global: in the (o,ph) layout a lane's per-n W
//    slice is CONTIGUOUS 256B (float offset = lane*64). 16 dwordx4/nn/lane;
//    the wave's 16 instrs cover one dense 16KB tile. All 8 waves of a block
//    read the same tile at ~the same nn -> L1 (32KB) serves the reuse; L2/L3
//    dedup across blocks (same as before: FETCH was 35MB with 2 blocks/tile).
//  - ZERO barriers in the nn loop (only one after x staging). No ds_write/
//    ds_read for W, no swizzle, no 2.1M bank conflicts, no lockstep.
//  - register budget vs the (512,2) 128-cap: W read as two 32-reg half-tiles;
//    v loaded TRANSIENTLY after pr completes (R5's proven pass-2 pattern; the
//    R6 hoist would put peak at ~150 -> spill). Peak ~= s_r32+pr32+
//    max(W32,v32)+misc ~= 115.
//  - x: LDS broadcast read -> readfirstlane -> SGPR FMA operands (no VGPR
//    cost, proven R4-R7).
// Tripwires: FETCH>150MB = stride amplification (revert direction);
// fused >=42us clean = concurrency theory dead (pivot to bf16-split MFMA).
template <int MODE, bool ATOMIC>
__global__ __launch_bounds__(512, 2)
void fused_pass(const float* __restrict__ x, const float* __restrict__ W,
                const float* __restrict__ v_in, float* __restrict__ s_out,
                float* __restrict__ rw_out) {
  __shared__ __align__(16) float x_lds[32 * 64];      // 8 KB: [b_local][n*8+i]
  const int tid  = threadIdx.x;
  const int lane = tid & 63;
  const int wu   = __builtin_amdgcn_readfirstlane(tid >> 6);  // 0..7
  const int o    = lane >> 1;   // 0..31 output capsule
  const int ph   = lane & 1;    // p-half: p = ph*8 + pp
  const int cn   = blockIdx.x >> 1;      // n-chunk 0..255
  const int bh   = blockIdx.x & 1;       // b-half
  const int n0   = cn * CHUNK_;
  const int b0w  = bh * 32 + wu * 4;     // wave's first b (wave-uniform)

  float s_r[4][8];
  #pragma unroll
  for (int bb = 0; bb < 4; ++bb)
    #pragma unroll
    for (int pp = 0; pp < 8; ++pp) s_r[bb][pp] = 0.0f;

  // prologue: stage x once (block's 32 b x 64 floats, coalesced), one barrier.
  {
    const int bl = tid >> 4;    // b_local 0..31
    const int ch = tid & 15;    // float4 chunk within b's 64 floats
    const float4 xv = *(const float4*)(
        x + (size_t)(bh * 32 + bl) * (N_ * DI_) + n0 * DI_ + ch * 4);
    *(float4*)&x_lds[bl * 64 + ch * 4] = xv;
  }
  __syncthreads();

  // lane's W stream base: float offset lane*64 within each 4096-float tile
  const float* wlane = W + (size_t)n0 * WSLICE_ + lane * 64;

  #pragma unroll 1
  for (int nn = 0; nn < CHUNK_; ++nn) {
    const int n = n0 + nn;
    const float* wp = wlane + (size_t)nn * WSLICE_;

    // x: broadcast ds_read -> SGPRs via readfirstlane
    float xs[4][8];
    #pragma unroll
    for (int bb = 0; bb < 4; ++bb) {
      const int xb = (wu * 4 + bb) * 64 + nn * 8;
      const float4 xa = *(const float4*)&x_lds[xb];
      const float4 xc = *(const float4*)&x_lds[xb + 4];
      xs[bb][0] = rfl(xa.x); xs[bb][1] = rfl(xa.y);
      xs[bb][2] = rfl(xa.z); xs[bb][3] = rfl(xa.w);
      xs[bb][4] = rfl(xc.x); xs[bb][5] = rfl(xc.y);
      xs[bb][6] = rfl(xc.z); xs[bb][7] = rfl(xc.w);
    }

    // pass 1: predictions; W streamed in two 32-reg half-tiles (pressure cap)
    float pr[4][8];
    #pragma unroll
    for (int h = 0; h < 2; ++h) {
      float4 wr0 = *(const float4*)(wp + (h * 8 + 0) * 4);
      float4 wr1 = *(const float4*)(wp + (h * 8 + 1) * 4);
      float4 wr2 = *(const float4*)(wp + (h * 8 + 2) * 4);
      float4 wr3 = *(const float4*)(wp + (h * 8 + 3) * 4);
      float4 wr4 = *(const float4*)(wp + (h * 8 + 4) * 4);
      float4 wr5 = *(const float4*)(wp + (h * 8 + 5) * 4);
      float4 wr6 = *(const float4*)(wp + (h * 8 + 6) * 4);
      float4 wr7 = *(const float4*)(wp + (h * 8 + 7) * 4);
      #pragma unroll
      for (int q = 0; q < 4; ++q) {        // pp = h*4 + q
        const float4 w0 = (q == 0) ? wr0 : (q == 1) ? wr2 : (q == 2) ? wr4 : wr6;
        const float4 w1 = (q == 0) ? wr1 : (q == 1) ? wr3 : (q == 2) ? wr5 : wr7;
        #pragma unroll
        for (int bb = 0; bb < 4; ++bb) {
          float pv = w0.x * xs[bb][0];
          pv = __builtin_fmaf(w0.y, xs[bb][1], pv);
          pv = __builtin_fmaf(w0.z, xs[bb][2], pv);
          pv = __builtin_fmaf(w0.w, xs[bb][3], pv);
          pv = __builtin_fmaf(w1.x, xs[bb][4], pv);
          pv = __builtin_fmaf(w1.y, xs[bb][5], pv);
          pv = __builtin_fmaf(w1.z, xs[bb][6], pv);
          pv = __builtin_fmaf(w1.w, xs[bb][7], pv);
          if (MODE == 0) s_r[bb][h * 4 + q] += pv;
          else           pr[bb][h * 4 + q] = pv;
        }
      }
    }

    // pass 2 (MODE!=0): transient v load (32 regs AFTER W regs die), v-dot,
    // in-wave DPP softmax, accumulate.
    if (MODE != 0) {
      float4 va[4], vc[4];
      #pragma unroll
      for (int bb = 0; bb < 4; ++bb) {
        const float4* vp =
            (const float4*)(v_in + (size_t)(b0w + bb) * OP_ + lane * 8);
        va[bb] = vp[0];
        vc[bb] = vp[1];
      }
      #pragma unroll
      for (int bb = 0; bb < 4; ++bb) {
        float acc = pr[bb][0] * va[bb].x;
        acc = __builtin_fmaf(pr[bb][1], va[bb].y, acc);
        acc = __builtin_fmaf(pr[bb][2], va[bb].z, acc);
        acc = __builtin_fmaf(pr[bb][3], va[bb].w, acc);
        acc = __builtin_fmaf(pr[bb][4], vc[bb].x, acc);
        acc = __builtin_fmaf(pr[bb][5], vc[bb].y, acc);
        acc = __builtin_fmaf(pr[bb][6], vc[bb].z, acc);
        acc = __builtin_fmaf(pr[bb][7], vc[bb].w, acc);
        // full logit = both p-halves (quad_perm xor1 pairs lanes 2o/2o+1)
        const float full = dpp_add<0xB1>(acc);
        const float e = __expf(full);
        // sum over all 64 lanes = 2*Z[b] (each o counted twice via ph)
        float srow = e;
        srow = dpp_add<0x121>(srow);
        srow = dpp_add<0x122>(srow);
        srow = dpp_add<0x124>(srow);
        srow = dpp_add<0x128>(srow);
        float t16 = srow + __shfl_xor(srow, 16);
        const float S = t16 + __shfl_xor(t16, 32);   // = 2*Z
        const float rw = (2.0f * e) / S;             // e/Z
        #pragma unroll
        for (int pp = 0; pp < 8; ++pp)
          s_r[bb][pp] = __builtin_fmaf(rw, pr[bb][pp], s_r[bb][pp]);
        if (MODE == 2) {
          if (ph == 0)
            rw_out[((size_t)(b0w + bb) * N_ + n) * O_ + o] = rw;
        }
      }
    }
  }

  // epilogue, spart layout [cn][b][h][lane][4]: each float4 store is
  // base + lane*16B -> contiguous 1KB per instr.
  if (ATOMIC) {
    #pragma unroll
    for (int bb = 0; bb < 4; ++bb) {
      #pragma unroll
      for (int h = 0; h < 2; ++h)
        #pragma unroll
        for (int j = 0; j < 4; ++j)
          atomicAdd(&s_out[(size_t)(b0w + bb) * 512 + h * 256 + lane * 4 + j],
                    s_r[bb][h * 4 + j]);
    }
  } else {
    #pragma unroll
    for (int bb = 0; bb < 4; ++bb) {
      float* sp = s_out + (size_t)cn * M_ + (size_t)(b0w + bb) * 512 + lane * 4;
      float4 st0, st1;
      st0.x = s_r[bb][0]; st0.y = s_r[bb][1]; st0.z = s_r[bb][2]; st0.w = s_r[bb][3];
      st1.x = s_r[bb][4]; st1.y = s_r[bb][5]; st1.z = s_r[bb][6]; st1.w = s_r[bb][7];
      *(float4*)sp = st0;
      *(float4*)(sp + 256) = st1;
    }
  }
}

// stage-1 reduction: P[K][M_] -> P2[16][M_]; grid 16 groups x 16 m-chunks.
// (element-wise over flat M_, layout-agnostic)
__global__ __launch_bounds__(1024)
void reduce1(const float* __restrict__ spart, float* __restrict__ p2, int K) {
  const int g  = blockIdx.x >> 4;
  const int mc = blockIdx.x & 15;
  const int kpg = K >> 4;
  const int m0 = mc * 2048 + threadIdx.x;
  float a0 = 0.0f, a1 = 0.0f;
  const float* p = spart + (size_t)(g * kpg) * M_;
  for (int k = 0; k < kpg; ++k) {
    a0 += p[(size_t)k * M_ + m0];
    a1 += p[(size_t)k * M_ + m0 + 1024];
  }
  p2[(size_t)g * M_ + m0]        = a0;
  p2[(size_t)g * M_ + m0 + 1024] = a1;
}

// sum ngroups (stride M_) + squash; optional v_add / zero_buf.
// src layout from fused_pass: idx(b,o,p) = b*512 + ((p>>2)&1)*256 +
// (2*o + (p>>3))*4 + (p&3).
__global__ __launch_bounds__(1024)
void v_kernel(const float* __restrict__ src, int ngroups, float scale,
              const float* __restrict__ v_add, float* __restrict__ v_out,
              float* __restrict__ zero_buf) {
  __shared__ float sq[P_ * 65];
  const int t = threadIdx.x;
  const int p = t & 15;
  const int b = t >> 4;
  const int o = blockIdx.x;
  const int q = o * P_ + p;
  const int idx_src = b * 512 + ((p >> 2) & 1) * 256 + (2 * o + (p >> 3)) * 4 +
                      (p & 3);
  float acc = 0.0f;
  for (int g = 0; g < ngroups; ++g)
    acc += src[(size_t)g * M_ + idx_src];
  acc *= scale;
  sq[p * 65 + b] = acc * acc;
  if (zero_buf) zero_buf[blockIdx.x * 1024 + t] = 0.0f;
  __syncthreads();
  float s2 = 0.0f;
  #pragma unroll
  for (int pp = 0; pp < P_; ++pp) s2 += sq[pp * 65 + b];
  float sc = (s2 / (1.0f + s2)) / sqrtf(s2 + 1e-7f);
  float v = acc * sc;
  const int idx = b * OP_ + q;   // v layout [b][o][p]
  v_out[idx] = v + (v_add ? v_add[idx] : 0.0f);
}

extern "C" void kernel_launch(void* const* d_in, const int* in_sizes, int n_in,
                              void* d_out, int out_size, void* d_ws, size_t ws_size,
                              hipStream_t stream) {
  (void)in_sizes; (void)n_in; (void)out_size;
  const float* x = (const float*)d_in[0];
  const float* W = (const float*)d_in[1];
  float* out_v  = (float*)d_out;                       // [64][32][16]
  float* out_rw = out_v + (size_t)B_ * O_ * P_;        // [64][2048][32]
  float* vws   = (float*)d_ws;                         // v0
  float* vsum  = vws + M_;                             // v0+v1
  float* p2    = vsum + M_;                            // 16 * M_
  float* spart = p2 + 16 * M_;                         // NBLK_ * M_

  const size_t need = (size_t)(2 * M_ + 16 * M_ + (size_t)NBLK_ * M_) * 4;

  dim3 gF(2 * NBLK_), bF(512), gV(O_), bV(1024), gR(256), bR(1024);
  if (ws_size >= need) {
    fused_pass<0, false><<<gF, bF, 0, stream>>>(x, W, nullptr, spart, nullptr);
    reduce1<<<gR, bR, 0, stream>>>(spart, p2, NBLK_);
    v_kernel<<<gV, bV, 0, stream>>>(p2, 16, 1.0f / 32.0f, nullptr, vws, nullptr);
    fused_pass<1, false><<<gF, bF, 0, stream>>>(x, W, vws, spart, nullptr);
    reduce1<<<gR, bR, 0, stream>>>(spart, p2, NBLK_);
    v_kernel<<<gV, bV, 0, stream>>>(p2, 16, 1.0f, vws, vsum, nullptr);
    fused_pass<2, false><<<gF, bF, 0, stream>>>(x, W, vsum, spart, out_rw);
    reduce1<<<gR, bR, 0, stream>>>(spart, p2, NBLK_);
    v_kernel<<<gV, bV, 0, stream>>>(p2, 16, 1.0f, nullptr, out_v, nullptr);
  } else {
    // atomic fallback for small ws
    float* sAb = p2;
    float* sBb = sAb + M_;
    hipMemsetAsync(sAb, 0, (size_t)M_ * sizeof(float), stream);
    fused_pass<0, true><<<gF, bF, 0, stream>>>(x, W, nullptr, sAb, nullptr);
    v_kernel<<<gV, bV, 0, stream>>>(sAb, 1, 1.0f / 32.0f, nullptr, vws, sBb);
    fused_pass<1, true><<<gF, bF, 0, stream>>>(x, W, vws, sBb, nullptr);
    v_kernel<<<gV, bV, 0, stream>>>(sBb, 1, 1.0f, vws, vsum, sAb);
    fused_pass<2, true><<<gF, bF, 0, stream>>>(x, W, vsum, sAb, out_rw);
    v_kernel<<<gV, bV, 0, stream>>>(sAb, 1, 1.0f, nullptr, out_v, nullptr);
  }
}

// Round 9
// 306.790 us; speedup vs baseline: 1.0035x; 1.0035x over previous
//
#include <hip/hip_runtime.h>

typedef __attribute__((ext_vector_type(4))) float f32x4;
typedef __attribute__((ext_vector_type(8))) short bf16x8;

static constexpr int B_    = 64;
static constexpr int N_    = 2048;
static constexpr int DI_   = 8;
static constexpr int O_    = 32;
static constexpr int P_    = 16;
static constexpr int OP_   = O_ * P_;      // 512
static constexpr int M_    = OP_ * B_;     // 32768 s elements
static constexpr int CHUNK_ = 8;
static constexpr int NBLK_  = N_ / CHUNK_; // 256 n-chunks

__device__ __forceinline__ int rfl_i(int v) {
  return __builtin_amdgcn_readfirstlane(v);
}

// Split 8 fp32 into bf16 hi (truncation) + bf16 lo (truncated residual).
// W*x ~= Whi*xhi + Whi*xlo + Wlo*xhi; residual ~2^-16 relative (safe vs fp32
// tolerance). Truncation (not RNE) keeps Sterbenz-exact residuals and costs
// only shifts/ands (no perm builtin dependency).
__device__ __forceinline__ void cvt_hilo(f32x4 a, f32x4 b, bf16x8& hi, bf16x8& lo) {
  uint32_t u0 = __float_as_uint(a[0]), u1 = __float_as_uint(a[1]);
  uint32_t u2 = __float_as_uint(a[2]), u3 = __float_as_uint(a[3]);
  uint32_t u4 = __float_as_uint(b[0]), u5 = __float_as_uint(b[1]);
  uint32_t u6 = __float_as_uint(b[2]), u7 = __float_as_uint(b[3]);
  union { uint32_t u[4]; bf16x8 v; } H, L;
  H.u[0] = (u0 >> 16) | (u1 & 0xFFFF0000u);
  H.u[1] = (u2 >> 16) | (u3 & 0xFFFF0000u);
  H.u[2] = (u4 >> 16) | (u5 & 0xFFFF0000u);
  H.u[3] = (u6 >> 16) | (u7 & 0xFFFF0000u);
  float l0 = a[0] - __uint_as_float(u0 & 0xFFFF0000u);
  float l1 = a[1] - __uint_as_float(u1 & 0xFFFF0000u);
  float l2 = a[2] - __uint_as_float(u2 & 0xFFFF0000u);
  float l3 = a[3] - __uint_as_float(u3 & 0xFFFF0000u);
  float l4 = b[0] - __uint_as_float(u4 & 0xFFFF0000u);
  float l5 = b[1] - __uint_as_float(u5 & 0xFFFF0000u);
  float l6 = b[2] - __uint_as_float(u6 & 0xFFFF0000u);
  float l7 = b[3] - __uint_as_float(u7 & 0xFFFF0000u);
  L.u[0] = (__float_as_uint(l0) >> 16) | (__float_as_uint(l1) & 0xFFFF0000u);
  L.u[1] = (__float_as_uint(l2) >> 16) | (__float_as_uint(l3) & 0xFFFF0000u);
  L.u[2] = (__float_as_uint(l4) >> 16) | (__float_as_uint(l5) & 0xFFFF0000u);
  L.u[3] = (__float_as_uint(l6) >> 16) | (__float_as_uint(l7) & 0xFFFF0000u);
  hi = H.v;
  lo = L.v;
}

#define MFMA16(a, b, c) __builtin_amdgcn_mfma_f32_16x16x32_bf16((a), (b), (c), 0, 0, 0)

// R9: MFMA pivot. R1/R4/R7/R8 (46-72us, all pipes <40%) proved the fp32-VALU
// preds computation is the structural floor. preds per (n,o) is one
// 16x16x32 bf16 MFMA tile: A = W[n,o] (16p x 8i, k 8..31 zero),
// B = x[:,n] (8i x 16b), D[p][b]. hi/lo split for fp32-grade precision.
// Layout safety: A and B share the same (lane,elem)->k map, so any k-perm
// cancels; m/n-dims forced to lane&15; C/D = m89-verified (col=lane&15=b,
// row=(lane>>4)*4+reg=p). One 16-q tile == one o => scalar rw per tile.
// Block (512,2): 8 waves = 4 qg x 2 bt; covers bh (32 b) x all 32 o x 8 n.
// MODE0: MFMA-chain straight into s accumulator, ZERO loop barriers.
// MODE1/2: pr per tile, v-dot in-fragment + shfl_xor(16,32), Z via 1KB LDS
// (double-buffered, one barrier/n), s += rw*pr.
// Epilogue: per-wave 1KB LDS transpose of D-fragments -> full-sector b128
// stores; spart layout becomes clean [cn][b][o][p] (v_kernel idx trivial).
template <int MODE, bool ATOMIC>
__global__ __launch_bounds__(512, 2)
void fused_pass(const float* __restrict__ x, const float* __restrict__ W,
                const float* __restrict__ v_in, float* __restrict__ s_out,
                float* __restrict__ rw_out) {
  __shared__ __align__(16) float x_lds[32 * 64];      // 8 KB [b_local][n*8+i]
  __shared__ __align__(16) float z_lds[2][32][4];     // 1 KB, dbuf Z partials
  __shared__ __align__(16) float epi[8][256];         // 8 KB transpose scratch
  const int tid  = threadIdx.x;
  const int lane = tid & 63;
  const int wu   = rfl_i(tid >> 6);      // 0..7
  const int qg   = wu >> 1;              // o-group: o = qg*8 + t
  const int bt   = wu & 1;               // b-16-tile within the b-half
  const int lb   = lane & 15;            // D-col sub-index / loader row
  const int kq   = lane >> 4;            // D-row quad: p = kq*4 + reg
  const int cn   = blockIdx.x >> 1;      // n-chunk 0..255
  const int bh   = blockIdx.x & 1;       // b-half
  const int n0   = cn * CHUNK_;
  const int bcol = bh * 32 + bt * 16 + lb;   // this lane's batch column

  // stage x once (block's 32 b x 64 floats, coalesced)
  {
    const int bl = tid >> 4;
    const int ch = tid & 15;
    *(f32x4*)&x_lds[bl * 64 + ch * 4] = *(const f32x4*)(
        x + (size_t)(bh * 32 + bl) * (N_ * DI_) + n0 * DI_ + ch * 4);
  }
  __syncthreads();

  f32x4 s_f[8];
  #pragma unroll
  for (int t = 0; t < 8; ++t) s_f[t] = (f32x4){0.f, 0.f, 0.f, 0.f};

  // frags: lanes >=16 are the k>=8 zero-pad; init once, never overwritten there
  bf16x8 z8 = {0, 0, 0, 0, 0, 0, 0, 0};
  bf16x8 Ahi = z8, Alo = z8, Bhi = z8, Blo = z8;

  #pragma unroll 1
  for (int nn = 0; nn < CHUNK_; ++nn) {
    const int n = n0 + nn;

    if (lane < 16) {   // B = x[i][b]: 8 contiguous floats per b
      f32x4 xa = *(const f32x4*)&x_lds[(bt * 16 + lane) * 64 + nn * 8];
      f32x4 xb = *(const f32x4*)&x_lds[(bt * 16 + lane) * 64 + nn * 8 + 4];
      cvt_hilo(xa, xb, Bhi, Blo);
    }

    f32x4 pr_f[8];
    float ef[8];
    float zacc = 0.0f;

    #pragma unroll
    for (int t = 0; t < 8; ++t) {
      const int o = qg * 8 + t;
      if (lane < 16) {  // A = W[n,o]: row p=lane, 8 contiguous i-floats
        const float* wp = W + ((size_t)n * 512 + o * 16 + lane) * 8;
        f32x4 wa = *(const f32x4*)wp;
        f32x4 wb = *(const f32x4*)(wp + 4);
        cvt_hilo(wa, wb, Ahi, Alo);
      }
      if (MODE == 0) {
        // chain hi/lo MFMAs straight into the s accumulator
        s_f[t] = MFMA16(Alo, Bhi, s_f[t]);
        s_f[t] = MFMA16(Ahi, Blo, s_f[t]);
        s_f[t] = MFMA16(Ahi, Bhi, s_f[t]);
      } else {
        f32x4 d = (f32x4){0.f, 0.f, 0.f, 0.f};
        d = MFMA16(Alo, Bhi, d);
        d = MFMA16(Ahi, Blo, d);
        d = MFMA16(Ahi, Bhi, d);
        pr_f[t] = d;
        // logit partial: lane has p = kq*4+reg for its b
        f32x4 vt = *(const f32x4*)(v_in + (size_t)bcol * OP_ + o * 16 + kq * 4);
        float dd = d[0] * vt[0];
        dd = __builtin_fmaf(d[1], vt[1], dd);
        dd = __builtin_fmaf(d[2], vt[2], dd);
        dd = __builtin_fmaf(d[3], vt[3], dd);
        dd += __shfl_xor(dd, 16);
        dd += __shfl_xor(dd, 32);        // full logit(b, o) in all lanes
        ef[t] = __expf(dd);
        zacc += ef[t];
      }
    }

    if (MODE != 0) {
      // Z over 32 o = 4 qg-wave partials per b; dbuf -> one barrier per n
      if (lane < 16) z_lds[nn & 1][bt * 16 + lane][qg] = zacc;
      __syncthreads();
      f32x4 zv = *(const f32x4*)&z_lds[nn & 1][bt * 16 + lb][0];
      const float rZ = 1.0f / (zv[0] + zv[1] + zv[2] + zv[3]);
      #pragma unroll
      for (int t = 0; t < 8; ++t) {
        const float rw = ef[t] * rZ;
        s_f[t][0] = __builtin_fmaf(rw, pr_f[t][0], s_f[t][0]);
        s_f[t][1] = __builtin_fmaf(rw, pr_f[t][1], s_f[t][1]);
        s_f[t][2] = __builtin_fmaf(rw, pr_f[t][2], s_f[t][2]);
        s_f[t][3] = __builtin_fmaf(rw, pr_f[t][3], s_f[t][3]);
      }
      if (MODE == 2) {
        if (lane < 16) {   // 32B contiguous per lane (o innermost)
          f32x4 r0, r1;
          r0[0] = ef[0] * rZ; r0[1] = ef[1] * rZ;
          r0[2] = ef[2] * rZ; r0[3] = ef[3] * rZ;
          r1[0] = ef[4] * rZ; r1[1] = ef[5] * rZ;
          r1[2] = ef[6] * rZ; r1[3] = ef[7] * rZ;
          float* rp = rw_out + ((size_t)bcol * N_ + n) * O_ + qg * 8;
          *(f32x4*)rp = r0;
          *(f32x4*)(rp + 4) = r1;
        }
      }
    }
  }

  // epilogue: per-wave LDS transpose of D-fragments -> full 64B-sector stores.
  // write word (kq*16+lb)*4+reg  <->  value s[p=kq*4+reg][b=lb]
  // read  word ((lane&3)*16+(lane>>2))*4  -> lane' = (b=lane>>2, pq=lane&3)
  {
    float* ep = &epi[wu][0];
    #pragma unroll
    for (int t = 0; t < 8; ++t) {
      const int o = qg * 8 + t;
      *(f32x4*)&ep[lane * 4] = s_f[t];
      asm volatile("s_waitcnt lgkmcnt(0)" ::: "memory");
      __builtin_amdgcn_sched_barrier(0);
      f32x4 rv = *(const f32x4*)&ep[((lane & 3) * 16 + (lane >> 2)) * 4];
      asm volatile("s_waitcnt lgkmcnt(0)" ::: "memory");
      __builtin_amdgcn_sched_barrier(0);
      const size_t qoff =
          (size_t)(bh * 32 + bt * 16 + (lane >> 2)) * OP_ + o * 16 + (lane & 3) * 4;
      if (ATOMIC) {
        atomicAdd(&s_out[qoff + 0], rv[0]);
        atomicAdd(&s_out[qoff + 1], rv[1]);
        atomicAdd(&s_out[qoff + 2], rv[2]);
        atomicAdd(&s_out[qoff + 3], rv[3]);
      } else {
        *(f32x4*)(s_out + (size_t)cn * M_ + qoff) = rv;
      }
    }
  }
}

// stage-1 reduction: P[K][M_] -> P2[16][M_]; grid 16 groups x 16 m-chunks.
// (element-wise over flat M_, layout-agnostic)
__global__ __launch_bounds__(1024)
void reduce1(const float* __restrict__ spart, float* __restrict__ p2, int K) {
  const int g  = blockIdx.x >> 4;
  const int mc = blockIdx.x & 15;
  const int kpg = K >> 4;
  const int m0 = mc * 2048 + threadIdx.x;
  float a0 = 0.0f, a1 = 0.0f;
  const float* p = spart + (size_t)(g * kpg) * M_;
  for (int k = 0; k < kpg; ++k) {
    a0 += p[(size_t)k * M_ + m0];
    a1 += p[(size_t)k * M_ + m0 + 1024];
  }
  p2[(size_t)g * M_ + m0]        = a0;
  p2[(size_t)g * M_ + m0 + 1024] = a1;
}

// sum ngroups (stride M_) + squash; optional v_add / zero_buf.
// spart layout is now clean [b][o][p] -> idx_src == output idx.
__global__ __launch_bounds__(1024)
void v_kernel(const float* __restrict__ src, int ngroups, float scale,
              const float* __restrict__ v_add, float* __restrict__ v_out,
              float* __restrict__ zero_buf) {
  __shared__ float sq[P_ * 65];
  const int t = threadIdx.x;
  const int p = t & 15;
  const int b = t >> 4;
  const int o = blockIdx.x;
  const int q = o * P_ + p;
  const int idx = b * OP_ + q;
  float acc = 0.0f;
  for (int g = 0; g < ngroups; ++g)
    acc += src[(size_t)g * M_ + idx];
  acc *= scale;
  sq[p * 65 + b] = acc * acc;
  if (zero_buf) zero_buf[blockIdx.x * 1024 + t] = 0.0f;
  __syncthreads();
  float s2 = 0.0f;
  #pragma unroll
  for (int pp = 0; pp < P_; ++pp) s2 += sq[pp * 65 + b];
  float sc = (s2 / (1.0f + s2)) / sqrtf(s2 + 1e-7f);
  float v = acc * sc;
  v_out[idx] = v + (v_add ? v_add[idx] : 0.0f);
}

extern "C" void kernel_launch(void* const* d_in, const int* in_sizes, int n_in,
                              void* d_out, int out_size, void* d_ws, size_t ws_size,
                              hipStream_t stream) {
  (void)in_sizes; (void)n_in; (void)out_size;
  const float* x = (const float*)d_in[0];
  const float* W = (const float*)d_in[1];
  float* out_v  = (float*)d_out;                       // [64][32][16]
  float* out_rw = out_v + (size_t)B_ * O_ * P_;        // [64][2048][32]
  float* vws   = (float*)d_ws;                         // v0
  float* vsum  = vws + M_;                             // v0+v1
  float* p2    = vsum + M_;                            // 16 * M_
  float* spart = p2 + 16 * M_;                         // NBLK_ * M_

  const size_t need = (size_t)(2 * M_ + 16 * M_ + (size_t)NBLK_ * M_) * 4;

  dim3 gF(2 * NBLK_), bF(512), gV(O_), bV(1024), gR(256), bR(1024);
  if (ws_size >= need) {
    fused_pass<0, false><<<gF, bF, 0, stream>>>(x, W, nullptr, spart, nullptr);
    reduce1<<<gR, bR, 0, stream>>>(spart, p2, NBLK_);
    v_kernel<<<gV, bV, 0, stream>>>(p2, 16, 1.0f / 32.0f, nullptr, vws, nullptr);
    fused_pass<1, false><<<gF, bF, 0, stream>>>(x, W, vws, spart, nullptr);
    reduce1<<<gR, bR, 0, stream>>>(spart, p2, NBLK_);
    v_kernel<<<gV, bV, 0, stream>>>(p2, 16, 1.0f, vws, vsum, nullptr);
    fused_pass<2, false><<<gF, bF, 0, stream>>>(x, W, vsum, spart, out_rw);
    reduce1<<<gR, bR, 0, stream>>>(spart, p2, NBLK_);
    v_kernel<<<gV, bV, 0, stream>>>(p2, 16, 1.0f, nullptr, out_v, nullptr);
  } else {
    // atomic fallback for small ws
    float* sAb = p2;
    float* sBb = sAb + M_;
    hipMemsetAsync(sAb, 0, (size_t)M_ * sizeof(float), stream);
    fused_pass<0, true><<<gF, bF, 0, stream>>>(x, W, nullptr, sAb, nullptr);
    v_kernel<<<gV, bV, 0, stream>>>(sAb, 1, 1.0f / 32.0f, nullptr, vws, sBb);
    fused_pass<1, true><<<gF, bF, 0, stream>>>(x, W, vws, sBb, nullptr);
    v_kernel<<<gV, bV, 0, stream>>>(sBb, 1, 1.0f, vws, vsum, sAb);
    fused_pass<2, true><<<gF, bF, 0, stream>>>(x, W, vsum, sAb, out_rw);
    v_kernel<<<gV, bV, 0, stream>>>(sAb, 1, 1.0f, nullptr, out_v, nullptr);
  }
}